// Round 3
// baseline (514.985 us; speedup 1.0000x reference)
//
#include <hip/hip_runtime.h>

// Reference reduces to a center crop (coords are fp32-exact integers i+16.0):
//   data_out[b,c,i,j,k] = data[b,c,i+16,j+16,k+16]
//   seg_out  = seg[:, :, 16:176, 16:176, 16:176]
// Shapes: in 2x (4,2,192,192,192) f32, out 2x (4,2,160,160,160) f32 concat-flat.
//
// Ladder: R0 (2-deep MLP, 32000 blk, nt-everything) 161.7us; R1 (20-deep,
// 1280 blk, plain loads) 172.8us [grid imbalance]; R2 (8-deep, 8000 blk,
// nt-everything) 161.6us == R0. Three structures, same time, all pipes idle
// => wave-side exonerated; memory-system/pattern/cache-policy is the limit.
// R3: single variable vs R2 -- PLAIN loads (nt only on stores). Theory:
// nt-load's evict-first hint defeats L3 retention of the 314MB read stream
// across timed iterations and deviates from the m13 6.29TB/s copy recipe.
// nt kept on stores: output never re-read; keeps write stream from evicting
// the read stream out of MALL.

constexpr unsigned P    = 160;                 // patch edge
constexpr unsigned S    = 192;                 // source edge
constexpr unsigned OFF  = 16;                  // crop offset
constexpr unsigned BC   = 8;                   // 4*2 volumes per tensor
constexpr unsigned ROW4 = P / 4;               // 40 f4 per out row
constexpr unsigned SROW4   = S / 4;            // 48
constexpr unsigned SPLANE4 = S * S / 4;        // 9216
constexpr unsigned SVOL4   = S * S * S / 4;    // 1769472
constexpr unsigned OUT4 = BC * P * P * ROW4;   // 8,192,000 f4 per tensor

using f4 = __attribute__((ext_vector_type(4))) float;

__global__ __launch_bounds__(256) void crop_copy_kernel(
    const f4* __restrict__ data,
    const f4* __restrict__ seg,
    f4* __restrict__ out)
{
    const unsigned o0 = blockIdx.x * 1024u + threadIdx.x;  // + 256k, k=0..3

    unsigned src[4];
#pragma unroll
    for (unsigned k = 0; k < 4; ++k) {
        const unsigned o   = o0 + 256u * k;
        const unsigned w4  = o % ROW4;
        const unsigned row = o / ROW4;
        const unsigned h   = row % P;
        const unsigned t   = row / P;
        const unsigned d   = t % P;
        const unsigned bc  = t / P;
        src[k] = bc * SVOL4 + (d + OFF) * SPLANE4 + (h + OFF) * SROW4
               + (OFF / 4) + w4;
    }

    // 8 independent PLAIN loads in flight before any store (R3 change).
    f4 a0 = data[src[0]];
    f4 a1 = data[src[1]];
    f4 a2 = data[src[2]];
    f4 a3 = data[src[3]];
    f4 b0 = seg[src[0]];
    f4 b1 = seg[src[1]];
    f4 b2 = seg[src[2]];
    f4 b3 = seg[src[3]];

    __builtin_nontemporal_store(a0, &out[o0]);
    __builtin_nontemporal_store(a1, &out[o0 + 256u]);
    __builtin_nontemporal_store(a2, &out[o0 + 512u]);
    __builtin_nontemporal_store(a3, &out[o0 + 768u]);
    __builtin_nontemporal_store(b0, &out[o0 + OUT4]);
    __builtin_nontemporal_store(b1, &out[o0 + OUT4 + 256u]);
    __builtin_nontemporal_store(b2, &out[o0 + OUT4 + 512u]);
    __builtin_nontemporal_store(b3, &out[o0 + OUT4 + 768u]);
}

extern "C" void kernel_launch(void* const* d_in, const int* in_sizes, int n_in,
                              void* d_out, int out_size, void* d_ws, size_t ws_size,
                              hipStream_t stream)
{
    const f4* data = (const f4*)d_in[0];
    const f4* seg  = (const f4*)d_in[1];
    f4* out = (f4*)d_out;

    constexpr unsigned block = 256;
    constexpr unsigned grid  = OUT4 / 1024;    // 8000 blocks, no tail
    crop_copy_kernel<<<grid, block, 0, stream>>>(data, seg, out);
}

// Round 4
// 481.557 us; speedup vs baseline: 1.0694x; 1.0694x over previous
//
#include <hip/hip_runtime.h>

// Reference reduces to a center crop (coords are fp32-exact integers i+16.0):
//   data_out[b,c,i,j,k] = data[b,c,i+16,j+16,k+16]
//   seg_out  = seg[:, :, 16:176, 16:176, 16:176]
// Shapes: in 2x (4,2,192,192,192) f32, out 2x (4,2,160,160,160) f32 concat-flat.
//
// Ladder: R0 161.7 (2-deep, 32000blk, nt) | R1 172.8 (20-deep, 1280blk --
// imbalance) | R2 161.6 (8-deep, 8000blk, nt) | R3 165.8 (R2 + plain loads
// -- nt loads are better). All variants ~2.5 TB/s combined HBM while fill
// kernels hit 6.4 TB/s in the same capture. Wave structure/occupancy/MLP/
// flags exonerated. Last hypothesis: 4 concurrent lockstep address streams
// per wave (2R+2W, size-aligned buffers => congruent channel bits) degrade
// DRAM efficiency vs the 1-2 dense streams of fill/copy.
// R4: stream separation. Blocks [0,8000) copy data, [8000,16000) copy seg.
// Each block = 16KB contiguous dst from ONE src buffer => per-wave pattern
// is exactly the rocclr-copy shape (1R+1W dense). nt both (best flags).

constexpr unsigned P    = 160;                 // patch edge
constexpr unsigned S    = 192;                 // source edge
constexpr unsigned OFF  = 16;                  // crop offset
constexpr unsigned BC   = 8;                   // 4*2 volumes per tensor
constexpr unsigned ROW4 = P / 4;               // 40 f4 per out row
constexpr unsigned SROW4   = S / 4;            // 48
constexpr unsigned SPLANE4 = S * S / 4;        // 9216
constexpr unsigned SVOL4   = S * S * S / 4;    // 1769472
constexpr unsigned OUT4 = BC * P * P * ROW4;   // 8,192,000 f4 per tensor
constexpr unsigned GRID_HALF = OUT4 / 1024;    // 8000 blocks per tensor

using f4 = __attribute__((ext_vector_type(4))) float;

__global__ __launch_bounds__(256) void crop_copy_kernel(
    const f4* __restrict__ data,
    const f4* __restrict__ seg,
    f4* __restrict__ out)
{
    const bool is_seg  = blockIdx.x >= GRID_HALF;           // scalar branch
    const f4* __restrict__ src_buf = is_seg ? seg : data;
    f4* __restrict__ dst           = out + (is_seg ? OUT4 : 0u);
    const unsigned b  = blockIdx.x - (is_seg ? GRID_HALF : 0u);
    const unsigned o0 = b * 1024u + threadIdx.x;            // + 256k, k=0..3

    unsigned src[4];
#pragma unroll
    for (unsigned k = 0; k < 4; ++k) {
        const unsigned o   = o0 + 256u * k;
        const unsigned w4  = o % ROW4;
        const unsigned row = o / ROW4;
        const unsigned h   = row % P;
        const unsigned t   = row / P;
        const unsigned d   = t % P;
        const unsigned bc  = t / P;
        src[k] = bc * SVOL4 + (d + OFF) * SPLANE4 + (h + OFF) * SROW4
               + (OFF / 4) + w4;
    }

    // 4 independent loads in flight from ONE buffer, then 4 dense stores.
    f4 a0 = __builtin_nontemporal_load(&src_buf[src[0]]);
    f4 a1 = __builtin_nontemporal_load(&src_buf[src[1]]);
    f4 a2 = __builtin_nontemporal_load(&src_buf[src[2]]);
    f4 a3 = __builtin_nontemporal_load(&src_buf[src[3]]);

    __builtin_nontemporal_store(a0, &dst[o0]);
    __builtin_nontemporal_store(a1, &dst[o0 + 256u]);
    __builtin_nontemporal_store(a2, &dst[o0 + 512u]);
    __builtin_nontemporal_store(a3, &dst[o0 + 768u]);
}

extern "C" void kernel_launch(void* const* d_in, const int* in_sizes, int n_in,
                              void* d_out, int out_size, void* d_ws, size_t ws_size,
                              hipStream_t stream)
{
    const f4* data = (const f4*)d_in[0];
    const f4* seg  = (const f4*)d_in[1];
    f4* out = (f4*)d_out;

    constexpr unsigned block = 256;
    constexpr unsigned grid  = 2 * GRID_HALF;  // 16000 blocks, no tail
    crop_copy_kernel<<<grid, block, 0, stream>>>(data, seg, out);
}